// Round 9
// baseline (2031.119 us; speedup 1.0000x reference)
//
#include <hip/hip_runtime.h>
#include <math.h>

#define HH 512
#define BB 64
#define SS 48
#define EE 512
#define G4 2048
#define EPSF 1e-5f
#define AGENT __HIP_MEMORY_SCOPE_AGENT

__device__ __forceinline__ float aload(const float* p) {
  return __hip_atomic_load(p, __ATOMIC_RELAXED, AGENT);   // sc1: MALL-coherent
}
__device__ __forceinline__ void astore(float* p, float v) {
  __hip_atomic_store(p, v, __ATOMIC_RELAXED, AGENT);
}

// ---- fast transcendentals (v_exp_f32 = 2^x, v_rcp_f32) ----
__device__ __forceinline__ float fsigmoid(float x) {
  float t = __builtin_amdgcn_exp2f(x * -1.44269504088896f);
  return __builtin_amdgcn_rcpf(1.f + t);
}
__device__ __forceinline__ float ftanh(float x) {
  x = fminf(fmaxf(x, -10.f), 10.f);
  float t = __builtin_amdgcn_exp2f(x * 2.88539008177793f);  // e^(2x)
  return (t - 1.f) * __builtin_amdgcn_rcpf(t + 1.f);
}

// counting barrier (preamble only)
__device__ __forceinline__ void gsync(int* c, int target) {
  __builtin_amdgcn_s_waitcnt(0);
  __syncthreads();
  if (threadIdx.x == 0) {
    __hip_atomic_fetch_add(c, 1, __ATOMIC_RELEASE, AGENT);
    int spins = 0;
    while (__hip_atomic_load(c, __ATOMIC_RELAXED, AGENT) < target) {
      __builtin_amdgcn_s_sleep(2);
      if (++spins > (1 << 21)) break;
    }
    (void)__hip_atomic_load(c, __ATOMIC_ACQUIRE, AGENT);
  }
  __syncthreads();
}

// ======== phase A: layer-0 input projection, full S, both dirs ========
__global__ __launch_bounds__(256)
void gemm_ih0(const float* __restrict__ x, const float* __restrict__ w_ih0,
              float* __restrict__ G0) {
  __shared__ float As[16][65];
  __shared__ float Bs[16][65];
  const int m0 = blockIdx.y * 64;
  const int d  = m0 / (BB * SS);
  const float* Wm = w_ih0 + (size_t)d * G4 * EE;
  const int bn = blockIdx.x * 64;
  const int tid = threadIdx.x;
  const int lrow = tid >> 2;
  const int lkk  = (tid & 3) << 2;
  const int tx = tid & 15;
  const int ty = tid >> 4;
  int m  = m0 + lrow;
  int r  = m - d * (BB * SS);
  int b  = r / SS;
  int tl = r - b * SS;
  int s  = d ? (SS - 1 - tl) : tl;
  const float* arow = x + ((size_t)b * SS + s) * EE;

  float acc[4][4] = {};
  for (int k0 = 0; k0 < EE; k0 += 16) {
    float4 av = *(const float4*)(arow + k0 + lkk);
    float4 bv = *(const float4*)(Wm + (size_t)(bn + lrow) * EE + k0 + lkk);
    As[lkk+0][lrow] = av.x; As[lkk+1][lrow] = av.y; As[lkk+2][lrow] = av.z; As[lkk+3][lrow] = av.w;
    Bs[lkk+0][lrow] = bv.x; Bs[lkk+1][lrow] = bv.y; Bs[lkk+2][lrow] = bv.z; Bs[lkk+3][lrow] = bv.w;
    __syncthreads();
    #pragma unroll
    for (int k = 0; k < 16; ++k) {
      float a[4], bbv[4];
      #pragma unroll
      for (int i = 0; i < 4; ++i) a[i] = As[k][ty*4+i];
      #pragma unroll
      for (int j = 0; j < 4; ++j) bbv[j] = Bs[k][tx*4+j];
      #pragma unroll
      for (int i = 0; i < 4; ++i)
        #pragma unroll
        for (int j = 0; j < 4; ++j) acc[i][j] += a[i]*bbv[j];
    }
    __syncthreads();
  }
  for (int i = 0; i < 4; ++i)
    for (int j = 0; j < 4; ++j)
      G0[(size_t)(m0 + ty*4 + i) * G4 + bn + tx*4 + j] = acc[i][j];
}

// ======== in-place LayerNorm on rows of 2048 ========
__global__ __launch_bounds__(256)
void ln_rows(float* __restrict__ X, const float* __restrict__ gamma,
             const float* __restrict__ beta, int rows_per_d) {
  __shared__ float red[8];
  const int row = blockIdx.x;
  const int d = row / rows_per_d;
  float* xr = X + (size_t)row * G4;
  const float* gg = gamma + (size_t)d * G4;
  const float* bb = beta  + (size_t)d * G4;
  float s = 0.f, q = 0.f;
  float v[8];
  #pragma unroll
  for (int it = 0; it < 8; ++it) {
    float xv = xr[threadIdx.x + it*256];
    v[it] = xv; s += xv; q += xv*xv;
  }
  #pragma unroll
  for (int off = 32; off > 0; off >>= 1) { s += __shfl_down(s, off); q += __shfl_down(q, off); }
  int lane = threadIdx.x & 63, wid = threadIdx.x >> 6;
  if (lane == 0) { red[wid] = s; red[4+wid] = q; }
  __syncthreads();
  float ts = red[0]+red[1]+red[2]+red[3];
  float tq = red[4]+red[5]+red[6]+red[7];
  float mu = ts * (1.f/G4);
  float rstd = rsqrtf(tq*(1.f/G4) - mu*mu + EPSF);
  #pragma unroll
  for (int it = 0; it < 8; ++it) {
    int jc = threadIdx.x + it*256;
    xr[jc] = (v[it]-mu)*rstd*gg[jc] + bb[jc];
  }
}

// ======== persistent scan: ONE exchange per step (R broadcast) ========
// group g = bb&7 = (d, bq); jb = bb>>3 in [0,32). Per step:
//   GEMV (block's 64 gate-cols) -> publish R values + per-row (s,q) partials
//   into the t&1 double buffer -> drain -> flag(t+1) -> 32-lane gather poll
//   -> read full R rows + partials -> REDUNDANT full cell update for all 512
//   cols (c/o live in LDS, never exchanged) -> local LN(c) -> h into hlds.
// Overwrite safety: publish into buf[t&1] is safe because poll(t-1)
// transitively proves all blocks consumed buf[(t-2)&1] (flag(t-1) follows
// GEMV(t-1) which used h(t-2) which required reading R(t-2)).
__global__ __launch_bounds__(1024, 4)
void persistR(const float* __restrict__ whh, const float* __restrict__ Gbuf,
              long g_row_stride, long g_t_stride,
              const float* __restrict__ lnhg, const float* __restrict__ lnhb,
              const float* __restrict__ lnog, const float* __restrict__ lnob,
              float* Rbuf, float* Rp, int* flags,
              float* fout, int nsteps,
              int mode1, const float* __restrict__ w_ih1,
              const float* __restrict__ xcb, float* g1pre,
              const float* __restrict__ ln_g1, const float* __restrict__ ln_b1,
              int* cnt_pre) {
  __shared__ float hlds[16][520];     // 33.3 KB (pad 8: h for GEMV)
  __shared__ float part[16][8][64];   // 32 KB
  __shared__ float c_lds[16][512];    // 32 KB (local full cell state)
  __shared__ float o_lds[16][512];    // 32 KB
  __shared__ float bcR[16][2];
  __shared__ float bcC[16][2];
  __shared__ float sred[32];

  const int bb = blockIdx.x;
  const int tid = threadIdx.x;

  // ---- mode1 preamble: layer-1 projection + LN(g1pre) ----
  if (mode1) {
    const int dp = bb & 1, nbp = bb >> 1;
    const int pb = tid >> 4, ns = tid & 15;
    const int col1 = nbp*16 + ns;
    const float* xrow = xcb + (size_t)pb * 1024;
    const float* wv_ = w_ih1 + ((size_t)dp*G4 + col1) * 1024;
    float a = 0.f;
    for (int k = 0; k < 1024; k += 4) {
      float4 xv = *(const float4*)(xrow + k);
      float4 wv4 = *(const float4*)(wv_ + k);
      a += xv.x*wv4.x + xv.y*wv4.y + xv.z*wv4.z + xv.w*wv4.w;
    }
    astore(g1pre + ((size_t)dp*BB + pb) * G4 + col1, a);
    gsync(cnt_pre + 0, 256);
    if (bb < 128) {
      const int ld = bb >> 6;
      float* xr = g1pre + (size_t)bb * G4;
      const float* gg = ln_g1 + (size_t)ld * G4;
      const float* be = ln_b1 + (size_t)ld * G4;
      float v0 = aload(xr + tid), v1 = aload(xr + tid + 1024);
      float s = v0 + v1, q = v0*v0 + v1*v1;
      #pragma unroll
      for (int off = 32; off > 0; off >>= 1) { s += __shfl_down(s, off); q += __shfl_down(q, off); }
      const int wv2 = tid >> 6;
      if ((tid & 63) == 0) { sred[wv2] = s; sred[16+wv2] = q; }
      __syncthreads();
      float ts = 0.f, tq = 0.f;
      #pragma unroll
      for (int i = 0; i < 16; ++i) { ts += sred[i]; tq += sred[16+i]; }
      float mu = ts * (1.f/G4);
      float rstd = rsqrtf(tq*(1.f/G4) - mu*mu + EPSF);
      astore(xr + tid,        (v0-mu)*rstd*gg[tid]      + be[tid]);
      astore(xr + tid + 1024, (v1-mu)*rstd*gg[tid+1024] + be[tid+1024]);
    }
    gsync(cnt_pre + 16, 256);
  }

  // ---- role decode ----
  const int g  = bb & 7;
  const int d  = g >> 2;
  const int bq = g & 3;
  const int jb = bb >> 3;
  const int rowbase = d*BB + bq*16;
  const int ke = tid >> 6, nl = tid & 63;       // GEMV: wave=k-slice, lane=col
  const int ncol = jb*16 + ((nl>>4) << 9) + (nl & 15);
  int* fL = flags + g*1024;                     // 32 slots x 32-int stride

  float wreg[32];
  {
    const float* wp = whh + ((size_t)d*G4 + ncol)*HH + (size_t)ke*32;
    #pragma unroll
    for (int i = 0; i < 32; ++i) wreg[i] = wp[i];
  }

  const int col = tid & 511, rh = tid >> 9;     // update/staging roles
  const int row16 = tid >> 5, j32 = tid & 31;   // reduce roles (tid<512)

  // ---- hoisted per-col step-invariant params (all threads) ----
  const float* lnhg_d = lnhg + (size_t)d*G4;
  const float* lnhb_d = lnhb + (size_t)d*G4;
  const float hg0 = lnhg_d[col],        hb0 = lnhb_d[col];
  const float hg1 = lnhg_d[HH+col],     hb1 = lnhb_d[HH+col];
  const float hg2 = lnhg_d[2*HH+col],   hb2 = lnhb_d[2*HH+col];
  const float hg3 = lnhg_d[3*HH+col],   hb3 = lnhb_d[3*HH+col];
  const float ogv = lnog[(size_t)d*HH + col];
  const float obv = lnob[(size_t)d*HH + col];

  // ---- init local state: h(-1) = 0, c(-1) = 0 ----
  {
    float* hz = &hlds[0][0];
    for (int u = tid; u < 16*520; u += 1024) hz[u] = 0.f;
    float* cz = &c_lds[0][0];
    for (int u = tid; u < 16*512; u += 1024) cz[u] = 0.f;
  }
  __syncthreads();

  for (int t = 0; t < nsteps; ++t) {
    float* RbufP = Rbuf + (size_t)(t & 1) * (128*2048);
    float* RpP   = Rp   + (size_t)(t & 1) * (128*64);

    // ---- GEMV over this block's 64 gate-cols; publish R + (s,q) partials --
    #pragma unroll
    for (int half = 0; half < 2; ++half) {
      #pragma unroll
      for (int b = 0; b < 8; ++b) {
        const float* hp = &hlds[half*8 + b][ke*32];
        float acc = 0.f;
        #pragma unroll
        for (int i4 = 0; i4 < 8; ++i4) {
          float4 h4 = *(const float4*)(hp + 4*i4);
          acc += h4.x*wreg[4*i4+0] + h4.y*wreg[4*i4+1]
               + h4.z*wreg[4*i4+2] + h4.w*wreg[4*i4+3];
        }
        part[ke][b][nl] = acc;
      }
      __syncthreads();
      if (tid < 512) {
        int b = tid >> 6, n2 = tid & 63;       // one wave per b
        float r = 0.f;
        #pragma unroll
        for (int k16 = 0; k16 < 16; ++k16) r += part[k16][b][n2];
        int row = half*8 + b;
        int nc2 = jb*16 + ((n2>>4) << 9) + (n2 & 15);
        astore(RbufP + (size_t)(rowbase + row)*2048 + nc2, r);
        float s = r, q = r*r;
        #pragma unroll
        for (int off = 32; off > 0; off >>= 1) { s += __shfl_down(s, off); q += __shfl_down(q, off); }
        if (n2 == 0) {
          astore(RpP + ((size_t)(rowbase + row)*32 + jb)*2 + 0, s);
          astore(RpP + ((size_t)(rowbase + row)*32 + jb)*2 + 1, q);
        }
      }
      __syncthreads();
    }

    // ---- the ONE exchange: drain -> flag -> gather-min poll ----
    // (publishes drained by the __syncthreads above: vmcnt(0) before barrier)
    if (tid == 0) __hip_atomic_store(fL + jb*32, t + 1, __ATOMIC_RELAXED, AGENT);
    if (tid < 32) {
      int spins = 0;
      for (;;) {
        int v = __hip_atomic_load(fL + tid*32, __ATOMIC_RELAXED, AGENT);
        #pragma unroll
        for (int off = 16; off > 0; off >>= 1) v = min(v, __shfl_down(v, off, 32));
        v = __shfl(v, 0, 32);
        if (v >= t + 1) break;
        __builtin_amdgcn_s_sleep(1);
        if (++spins > (1 << 22)) break;
      }
    }
    __syncthreads();

    // ---- reduce (s,q) partials -> (mu, rstd) over 2048 per row ----
    if (tid < 512) {
      float s = aload(RpP + ((size_t)(rowbase+row16)*32 + j32)*2 + 0);
      float q = aload(RpP + ((size_t)(rowbase+row16)*32 + j32)*2 + 1);
      #pragma unroll
      for (int off = 16; off > 0; off >>= 1) { s += __shfl_down(s, off, 32); q += __shfl_down(q, off, 32); }
      if (j32 == 0) {
        float mu = s * (1.f/G4);
        bcR[row16][0] = mu;
        bcR[row16][1] = rsqrtf(q*(1.f/G4) - mu*mu + EPSF);
      }
    }
    __syncthreads();

    // ---- redundant full cell update: batch-load all 32 R values first ----
    float Rv[32];
    #pragma unroll
    for (int i = 0; i < 8; ++i) {
      const float* Rrow = RbufP + (size_t)(rowbase + i*2 + rh)*2048 + col;
      Rv[4*i+0] = aload(Rrow);        Rv[4*i+1] = aload(Rrow + 512);
      Rv[4*i+2] = aload(Rrow + 1024); Rv[4*i+3] = aload(Rrow + 1536);
    }
    #pragma unroll
    for (int i = 0; i < 8; ++i) {
      const int r = i*2 + rh;
      const float* gr = Gbuf + (size_t)(rowbase + r)*g_row_stride
                             + (size_t)t*g_t_stride + col;
      float mu = bcR[r][0], rstd = bcR[r][1];
      float gi = gr[0]    + (Rv[4*i+0]-mu)*rstd*hg0 + hb0;
      float gf = gr[512]  + (Rv[4*i+1]-mu)*rstd*hg1 + hb1;
      float go = gr[1024] + (Rv[4*i+2]-mu)*rstd*hg2 + hb2;
      float gt = gr[1536] + (Rv[4*i+3]-mu)*rstd*hg3 + hb3;
      float iv = fsigmoid(gi), fv = fsigmoid(gf);
      float ov = fsigmoid(go), gv = ftanh(gt);
      float cn = fv * c_lds[r][col] + iv * gv;
      c_lds[r][col] = cn;
      o_lds[r][col] = ov;
    }
    __syncthreads();

    // ---- local LN(c) stats ----
    if (tid < 512) {
      float s = 0.f, q = 0.f;
      #pragma unroll
      for (int i = 0; i < 16; ++i) {
        float cvv = c_lds[row16][j32 + 32*i];
        s += cvv; q += cvv*cvv;
      }
      #pragma unroll
      for (int off = 16; off > 0; off >>= 1) { s += __shfl_down(s, off, 32); q += __shfl_down(q, off, 32); }
      if (j32 == 0) {
        float mu = s * (1.f/HH);
        bcC[row16][0] = mu;
        bcC[row16][1] = rsqrtf(q*(1.f/HH) - mu*mu + EPSF);
      }
    }
    __syncthreads();

    // ---- h(t) = o * tanh(LN(c)) -> hlds (GEMV input for t+1) ----
    #pragma unroll
    for (int i = 0; i < 8; ++i) {
      const int r = i*2 + rh;
      hlds[r][col] = o_lds[r][col]
          * ftanh((c_lds[r][col] - bcC[r][0]) * bcC[r][1] * ogv + obv);
    }
    __syncthreads();
  }

  // ---- final h -> output (jb==0 block of each group writes its 16 rows) ----
  if (jb == 0) {
    #pragma unroll
    for (int i = 0; i < 8; ++i) {
      const int r = i*2 + rh;
      fout[(size_t)(bq*16 + r) * 1024 + (size_t)d*512 + col] = hlds[r][col];
    }
  }
}

extern "C" void kernel_launch(void* const* d_in, const int* in_sizes, int n_in,
                              void* d_out, int out_size, void* d_ws, size_t ws_size,
                              hipStream_t stream) {
  const float* x        = (const float*)d_in[0];
  const float* w_ih0    = (const float*)d_in[2];
  const float* w_hh0    = (const float*)d_in[3];
  const float* ln_ih0_g = (const float*)d_in[4];
  const float* ln_ih0_b = (const float*)d_in[5];
  const float* ln_hh0_g = (const float*)d_in[6];
  const float* ln_hh0_b = (const float*)d_in[7];
  const float* ln_ho0_g = (const float*)d_in[8];
  const float* ln_ho0_b = (const float*)d_in[9];
  const float* w_ih1    = (const float*)d_in[10];
  const float* w_hh1    = (const float*)d_in[11];
  const float* ln_ih1_g = (const float*)d_in[12];
  const float* ln_ih1_b = (const float*)d_in[13];
  const float* ln_hh1_g = (const float*)d_in[14];
  const float* ln_hh1_b = (const float*)d_in[15];
  const float* ln_ho1_g = (const float*)d_in[16];
  const float* ln_ho1_b = (const float*)d_in[17];
  float* out = (float*)d_out;

  // ws (floats): G0 12.58M | g1pre 262K | xcb 64K | Rbuf 524K (2x dbuf) |
  //   Rp 16K (2x dbuf) | ints 16448 (flags L0/L1 + cnt_pre) ~= 53.9 MB
  // Rbuf/Rp need NO zero-init: every read is flag-guarded.
  float* G0    = (float*)d_ws;
  float* g1pre = G0 + (size_t)2*BB*SS*G4;
  float* xcb   = g1pre + (size_t)2*BB*G4;
  float* Rbuf  = xcb + (size_t)BB*1024;          // 2 x 128 x 2048
  float* Rp    = Rbuf + (size_t)2*128*2048;      // 2 x 128 x 32 x 2
  int*   ints  = (int*)(Rp + (size_t)2*128*64);
  int*   fL0     = ints;                 // 8 groups x 1024
  int*   fL1     = ints + 8192;
  int*   cnt_pre = ints + 16384;         // 64 ints

  // zero flags + counters only
  hipMemsetAsync(ints, 0, 16448*sizeof(int), stream);

  // phase A: G0 = LN(x @ w_ih0^T), time-reversal baked in for d=1
  hipLaunchKernelGGL(gemm_ih0, dim3(G4/64, (2*BB*SS)/64), dim3(256), 0, stream,
      x, w_ih0, G0);
  hipLaunchKernelGGL(ln_rows, dim3(2*BB*SS), dim3(256), 0, stream,
      G0, ln_ih0_g, ln_ih0_b, BB*SS);

  // layer 0 scan -> xcb
  hipLaunchKernelGGL(persistR, dim3(256), dim3(1024), 0, stream,
      w_hh0, G0, (long)SS*G4, (long)G4,
      ln_hh0_g, ln_hh0_b, ln_ho0_g, ln_ho0_b,
      Rbuf, Rp, fL0, xcb, SS,
      0, (const float*)nullptr, (const float*)nullptr, (float*)nullptr,
      (const float*)nullptr, (const float*)nullptr, (int*)nullptr);

  // layer 1: projection + LN in preamble, then scan (t-stride 0) -> out
  // (Rbuf/Rp reuse is safe: layer-1 reads are guarded by layer-1 flags,
  //  and kernel boundaries are stream-ordered.)
  hipLaunchKernelGGL(persistR, dim3(256), dim3(1024), 0, stream,
      w_hh1, g1pre, (long)G4, 0L,
      ln_hh1_g, ln_hh1_b, ln_ho1_g, ln_ho1_b,
      Rbuf, Rp, fL1, out, SS,
      1, w_ih1, xcb, g1pre, ln_ih1_g, ln_ih1_b, cnt_pre);
}